// Round 3
// baseline (358.248 us; speedup 1.0000x reference)
//
#include <hip/hip_runtime.h>

#define NN 4096
#define DD 512
#define TT 4096

typedef __bf16 bf16x8 __attribute__((ext_vector_type(8)));
typedef float f32x4 __attribute__((ext_vector_type(4)));

constexpr float INV_TEMP = 1.0f / 0.07f;

#define AS1(p) ((__attribute__((address_space(1))) const void*)(p))
#define AS3(p) ((__attribute__((address_space(3))) void*)(p))

// ---------------- normalize (fp32 -> normalized bf16) + triplet + accumulator init ----------------
__global__ __launch_bounds__(256) void k_normtrip(const float* __restrict__ emb,
                                                  __bf16* __restrict__ nemb,
                                                  const int* __restrict__ trip,
                                                  float* __restrict__ tl,
                                                  float* __restrict__ posR,
                                                  float* __restrict__ totR,
                                                  float* __restrict__ scal) {
    int wave = threadIdx.x >> 6, lane = threadIdx.x & 63;
    int row = blockIdx.x * 4 + wave;

    // zero the atomic accumulators this pipeline will add into (ws is poisoned)
    if (lane == 0) { posR[row] = 0.0f; totR[row] = 0.0f; }
    if (blockIdx.x == 0 && threadIdx.x < 3) scal[threadIdx.x] = 0.0f;

    // ---- triplet gathers (issue early, reduce late) ----
    int ia = trip[row * 3 + 0], ip = trip[row * 3 + 1], ig = trip[row * 3 + 2];
    const float4* pa = (const float4*)(emb + (size_t)ia * DD);
    const float4* pp = (const float4*)(emb + (size_t)ip * DD);
    const float4* pn = (const float4*)(emb + (size_t)ig * DD);
    float d1 = 0.0f, d2 = 0.0f;
    #pragma unroll
    for (int j = 0; j < 2; ++j) {
        float4 a = pa[lane * 2 + j];
        float4 p = pp[lane * 2 + j];
        float4 n = pn[lane * 2 + j];
        float dx;
        dx = a.x - p.x + 1e-6f; d1 += dx * dx;
        dx = a.y - p.y + 1e-6f; d1 += dx * dx;
        dx = a.z - p.z + 1e-6f; d1 += dx * dx;
        dx = a.w - p.w + 1e-6f; d1 += dx * dx;
        dx = a.x - n.x + 1e-6f; d2 += dx * dx;
        dx = a.y - n.y + 1e-6f; d2 += dx * dx;
        dx = a.z - n.z + 1e-6f; d2 += dx * dx;
        dx = a.w - n.w + 1e-6f; d2 += dx * dx;
    }

    // ---- normalize ----
    const float4* src = (const float4*)(emb + (size_t)row * DD);
    float4 x0 = src[lane * 2 + 0];
    float4 x1 = src[lane * 2 + 1];
    float ss = x0.x * x0.x + x0.y * x0.y + x0.z * x0.z + x0.w * x0.w +
               x1.x * x1.x + x1.y * x1.y + x1.z * x1.z + x1.w * x1.w;
    #pragma unroll
    for (int m = 1; m < 64; m <<= 1) ss += __shfl_xor(ss, m, 64);
    float inv = 1.0f / fmaxf(sqrtf(ss), 1e-8f);
    bf16x8 v;
    v[0] = (__bf16)(x0.x * inv); v[1] = (__bf16)(x0.y * inv);
    v[2] = (__bf16)(x0.z * inv); v[3] = (__bf16)(x0.w * inv);
    v[4] = (__bf16)(x1.x * inv); v[5] = (__bf16)(x1.y * inv);
    v[6] = (__bf16)(x1.z * inv); v[7] = (__bf16)(x1.w * inv);
    *(bf16x8*)(nemb + (size_t)row * DD + lane * 8) = v;

    // ---- triplet reduce + store ----
    #pragma unroll
    for (int m = 1; m < 64; m <<= 1) {
        d1 += __shfl_xor(d1, m, 64);
        d2 += __shfl_xor(d2, m, 64);
    }
    if (lane == 0) tl[row] = fmaxf(sqrtf(d1) - sqrtf(d2) + 0.5f, 0.0f);
}

// ---------------- contrast: 256x256 tile, BK=64, 8-wave, qn-resident-B pipeline ----------------
// vs previous round: B for BOTH qn-halves is loaded once per group at region1 and held in
// registers (bfr[2][2][2], +16 VGPR) -> LDS reads drop 32KB->24KB per wave-group (the min:
// A 128x64 + B 64x64 once each). Schedule per group g (par=g&1):
//   region1: ld A(h0) 8x b128 + B(h0)+B(h1) 8x b128; stage Ah1(g+1); lgk0; MFMA(qm0,qn0); barrier
//   region2: stage Bh1(g+1); MFMA(qm0,qn1)  [af,bfr held];
//            ld A(h1) 8x b128; stage Ah0(g+2), Bh0(g+2); lgk0; MFMA(qm1,qn0); MFMA(qm1,qn1);
//            vmcnt(4); barrier
// RAW ledger: at region2-end(g) queue = [Ah0(g+1),Bh0(g+1), Ah1(g+1),Bh1(g+1), Ah0(g+2),
// Bh0(g+2)] (12 instr); vmcnt(4) drains the first 4 stages -> everything group g+1 reads
// (region1: Ah0,Bh0,Bh1; region2: Ah1) is resident after the barrier. Prologue: 6 stages,
// vmcnt(4) drains first 4. Tail: group6 vmcnt(0) (only Ah1(7),Bh1(7),Ah0(7),Bh0(7) in queue).
// WAR ledger: Ah1(g+1) staged region1(g), old data last ds_read region2(g-1), barrier between;
// Bh1(g+1) staged region2(g), old read region1(g-1); Ah0/Bh0(g+2) staged region2(g), old read
// region1(g), region1-end barrier between. All reads complete before their barrier (lgkmcnt(0)
// precedes each barrier's MFMA block).

#define VMW(N) asm volatile("s_waitcnt vmcnt(" #N ")" ::: "memory")
#define NOVM ((void)0)

#define STAGE_A(T, H) do { \
    __builtin_amdgcn_global_load_lds(AS1(gA0 + (size_t)((H) * 128) * DD + (T) * 64), \
                                     AS3(lA0 + (((T) & 1) * 2 + (H)) * 8192), 16, 0, 0); \
    __builtin_amdgcn_global_load_lds(AS1(gA0 + (size_t)((H) * 128 + 8) * DD + (T) * 64), \
                                     AS3(lA0 + (((T) & 1) * 2 + (H)) * 8192 + 512), 16, 0, 0); \
} while (0)

#define STAGE_B(T, H) do { \
    __builtin_amdgcn_global_load_lds(AS1(gB0 + (size_t)((H) * 128) * DD + (T) * 64), \
                                     AS3(lB0 + (((T) & 1) * 2 + (H)) * 8192), 16, 0, 0); \
    __builtin_amdgcn_global_load_lds(AS1(gB0 + (size_t)((H) * 128 + 8) * DD + (T) * 64), \
                                     AS3(lB0 + (((T) & 1) * 2 + (H)) * 8192 + 512), 16, 0, 0); \
} while (0)

#define MFMA_Q(QM, QN) do { \
    _Pragma("unroll") \
    for (int kc_ = 0; kc_ < 2; ++kc_) { \
        _Pragma("unroll") \
        for (int fm_ = 0; fm_ < 4; ++fm_) { \
            _Pragma("unroll") \
            for (int fn_ = 0; fn_ < 2; ++fn_) \
                acc[QM][QN][fm_][fn_] = __builtin_amdgcn_mfma_f32_16x16x32_bf16( \
                    af[fm_][kc_], bfr[QN][fn_][kc_], acc[QM][QN][fm_][fn_], 0, 0, 0); \
        } \
    } \
} while (0)

#define GROUP(G, S12, S34, VMTAIL) do { \
    const __bf16* aB0 = aSm + (((G) & 1) * 2 + 0) * 8192; \
    const __bf16* bB0 = bSm + (((G) & 1) * 2 + 0) * 8192; \
    const __bf16* bB1 = bSm + (((G) & 1) * 2 + 1) * 8192; \
    _Pragma("unroll") \
    for (int fm_ = 0; fm_ < 4; ++fm_) { \
        af[fm_][0] = *(const bf16x8*)(aB0 + fm_ * 1024 + rdA0); \
        af[fm_][1] = *(const bf16x8*)(aB0 + fm_ * 1024 + rdA1); \
    } \
    _Pragma("unroll") \
    for (int fn_ = 0; fn_ < 2; ++fn_) { \
        bfr[0][fn_][0] = *(const bf16x8*)(bB0 + fn_ * 1024 + rdB0); \
        bfr[0][fn_][1] = *(const bf16x8*)(bB0 + fn_ * 1024 + rdB1); \
        bfr[1][fn_][0] = *(const bf16x8*)(bB1 + fn_ * 1024 + rdB0); \
        bfr[1][fn_][1] = *(const bf16x8*)(bB1 + fn_ * 1024 + rdB1); \
    } \
    if (S12) STAGE_A((G) + 1, 1); \
    asm volatile("s_waitcnt lgkmcnt(0)" ::: "memory"); \
    __builtin_amdgcn_sched_barrier(0); \
    __builtin_amdgcn_s_setprio(1); \
    MFMA_Q(0, 0); \
    __builtin_amdgcn_s_setprio(0); \
    asm volatile("" ::: "memory"); \
    __builtin_amdgcn_s_barrier(); \
    if (S12) STAGE_B((G) + 1, 1); \
    __builtin_amdgcn_s_setprio(1); \
    MFMA_Q(0, 1); \
    __builtin_amdgcn_s_setprio(0); \
    { \
        const __bf16* aB1 = aSm + (((G) & 1) * 2 + 1) * 8192; \
        _Pragma("unroll") \
        for (int fm_ = 0; fm_ < 4; ++fm_) { \
            af[fm_][0] = *(const bf16x8*)(aB1 + fm_ * 1024 + rdA0); \
            af[fm_][1] = *(const bf16x8*)(aB1 + fm_ * 1024 + rdA1); \
        } \
    } \
    if (S34) { STAGE_A((G) + 2, 0); STAGE_B((G) + 2, 0); } \
    asm volatile("s_waitcnt lgkmcnt(0)" ::: "memory"); \
    __builtin_amdgcn_sched_barrier(0); \
    __builtin_amdgcn_s_setprio(1); \
    MFMA_Q(1, 0); \
    MFMA_Q(1, 1); \
    __builtin_amdgcn_s_setprio(0); \
    VMTAIL; \
    asm volatile("" ::: "memory"); \
    __builtin_amdgcn_s_barrier(); \
} while (0)

__global__ __launch_bounds__(512, 2) void k_contrast(const __bf16* __restrict__ nemb,
                                                     const int* __restrict__ labels,
                                                     float* __restrict__ posR,
                                                     float* __restrict__ totR) {
    __shared__ __attribute__((aligned(16))) __bf16 aSm[4 * 8192];
    __shared__ __attribute__((aligned(16))) __bf16 bSm[4 * 8192];
    __shared__ int rlab[256];
    __shared__ int clab[256];

    int tid = threadIdx.x;
    int lane = tid & 63, wave = tid >> 6;
    int wr = wave >> 2, wc = wave & 3;
    int l15 = lane & 15, quad = lane >> 4;
    int swz = l15 & 7;

    // XCD-aware 2D swizzle: each XCD (bid&7) owns a 4x8 (rowblk x colblk) region.
    int bid = blockIdx.x;
    int xcd = bid & 7, idx = bid >> 3;
    int rowblk = (xcd >> 1) * 4 + (idx >> 3);
    int colblk = (xcd & 1) * 8 + (idx & 7);
    int row0 = rowblk * 256, col0 = colblk * 256;

    if (tid < 256) rlab[tid] = labels[row0 + tid];
    else           clab[tid - 256] = labels[col0 + tid - 256];

    // staging geometry: wave stages rows [wave*16, wave*16+16) of each 128-row half-tile.
    // LDS dest linear; SOURCE 16B-chunk pre-swizzled chunk ^= row&7 (involution w/ ds_read).
    int srow = wave * 16 + ((tid >> 3) & 7);
    int scol = ((tid & 7) ^ ((tid >> 3) & 7)) * 8;
    const __bf16* gA0 = nemb + (size_t)(row0 + srow) * DD + scol;
    const __bf16* gB0 = nemb + (size_t)(col0 + srow) * DD + scol;
    __bf16* lA0 = aSm + wave * 1024 + (tid & 63) * 8;
    __bf16* lB0 = bSm + wave * 1024 + (tid & 63) * 8;

    // ds_read offsets (elements), kc0/kc1 variants; fm/fn add compile-time +1024*k
    int rdA0 = (wr * 64 + l15) * 64 + ((quad ^ swz) * 8);
    int rdA1 = (wr * 64 + l15) * 64 + (((4 + quad) ^ swz) * 8);
    int rdB0 = (wc * 32 + l15) * 64 + ((quad ^ swz) * 8);
    int rdB1 = (wc * 32 + l15) * 64 + (((4 + quad) ^ swz) * 8);

    f32x4 acc[2][2][4][2];
    #pragma unroll
    for (int a = 0; a < 2; ++a)
        #pragma unroll
        for (int b = 0; b < 2; ++b)
            #pragma unroll
            for (int c = 0; c < 4; ++c)
                #pragma unroll
                for (int d = 0; d < 2; ++d) {
                    f32x4 z = {0.0f, 0.0f, 0.0f, 0.0f};
                    acc[a][b][c][d] = z;
                }

    bf16x8 af[4][2], bfr[2][2][2];

    // prologue: 6 half-tiles; vmcnt(4) -> Ah0(0),Bh0(0),Ah1(0),Bh1(0) resident
    STAGE_A(0, 0); STAGE_B(0, 0);
    STAGE_A(0, 1); STAGE_B(0, 1);
    STAGE_A(1, 0); STAGE_B(1, 0);
    VMW(4);
    asm volatile("" ::: "memory");
    __builtin_amdgcn_s_barrier();

    GROUP(0, 1, 1, VMW(4));
    GROUP(1, 1, 1, VMW(4));
    GROUP(2, 1, 1, VMW(4));
    GROUP(3, 1, 1, VMW(4));
    GROUP(4, 1, 1, VMW(4));
    GROUP(5, 1, 1, VMW(4));
    GROUP(6, 1, 0, VMW(0));
    GROUP(7, 0, 0, NOVM);

    // ---- epilogue: exp, mask, 2-stage lane reduce, per-row atomic accumulate ----
    #pragma unroll
    for (int qm = 0; qm < 2; ++qm)
    #pragma unroll
    for (int fm = 0; fm < 4; ++fm) {
        int rloc = qm * 128 + wr * 64 + fm * 16 + quad * 4;
        int gibase = row0 + rloc;
        int rl[4];
        #pragma unroll
        for (int v = 0; v < 4; ++v) rl[v] = rlab[rloc + v];
        float tv[4] = {0, 0, 0, 0}, pv[4] = {0, 0, 0, 0};
        #pragma unroll
        for (int qn = 0; qn < 2; ++qn)
        #pragma unroll
        for (int fn = 0; fn < 2; ++fn) {
            int cloc = qn * 128 + wc * 32 + fn * 16 + l15;
            int cl = clab[cloc];
            int gj = col0 + cloc;
            f32x4 a = acc[qm][qn][fm][fn];
            #pragma unroll
            for (int v = 0; v < 4; ++v) {
                float e = __expf(a[v] * INV_TEMP);
                tv[v] += e;
                bool match = (rl[v] == cl) && ((gibase + v) != gj);
                pv[v] += match ? e : 0.0f;
            }
        }
        #pragma unroll
        for (int m = 1; m < 4; m <<= 1) {
            #pragma unroll
            for (int v = 0; v < 4; ++v) {
                tv[v] += __shfl_xor(tv[v], m, 64);
                pv[v] += __shfl_xor(pv[v], m, 64);
            }
        }
        if ((l15 & 3) == 0) {
            #pragma unroll
            for (int v = 0; v < 4; ++v) {
                atomicAdd(&totR[gibase + v], tv[v]);
                atomicAdd(&posR[gibase + v], pv[v]);
            }
        }
    }
}

// ---------------- per-row loss: wave per row; validity via exact label-multiplicity scan ----
__global__ __launch_bounds__(256) void k_rowloss(const float* __restrict__ posR,
                                                 const float* __restrict__ totR,
                                                 const int* __restrict__ labels,
                                                 const float* __restrict__ tl,
                                                 float* __restrict__ scal) {
    int wave = threadIdx.x >> 6, lane = threadIdx.x & 63;
    int row = blockIdx.x * 4 + wave;
    int myLab = labels[row];
    int c = 0;
    #pragma unroll 8
    for (int j = lane; j < NN; j += 64) c += (labels[j] == myLab) ? 1 : 0;
    #pragma unroll
    for (int m = 1; m < 64; m <<= 1) c += __shfl_xor(c, m, 64);
    if (lane == 0) {
        bool valid = c > 1;   // c counts self; pos_mask row-sum > 0 <=> multiplicity > 1
        float p = posR[row], t = totR[row];
        float loss = valid ? -logf(p / (t + 1e-8f) + 1e-8f) : 0.0f;
        atomicAdd(&scal[0], loss);
        atomicAdd(&scal[1], valid ? 1.0f : 0.0f);
        atomicAdd(&scal[2], tl[row]);
    }
}

// ---------------- final: combine 3 scalars ----------------
__global__ __launch_bounds__(64) void k_final(const float* __restrict__ scal,
                                              float* __restrict__ out) {
    if (threadIdx.x == 0) {
        float SL = scal[0], SV = scal[1], ST = scal[2];
        float cont = (SV > 0.0f) ? (SL / SV) : 0.0f;
        float trip = ST * (1.0f / (float)TT);
        out[0] = cont + 0.3f * trip;
        out[1] = cont;
        out[2] = trip;
    }
}

extern "C" void kernel_launch(void* const* d_in, const int* in_sizes, int n_in,
                              void* d_out, int out_size, void* d_ws, size_t ws_size,
                              hipStream_t stream) {
    const float* emb = (const float*)d_in[0];
    const int* labels = (const int*)d_in[1];
    const int* trips = (const int*)d_in[2];
    float* out = (float*)d_out;
    char* ws = (char*)d_ws;

    __bf16* nemb = (__bf16*)(ws);                  // 4096*512*2 = 4194304 B
    float* posR  = (float*)(ws + 4194304);         // 16384 B
    float* totR  = (float*)(ws + 4210688);         // 16384 B
    float* tl    = (float*)(ws + 4227072);         // 16384 B
    float* scal  = (float*)(ws + 4243456);         // 12 B (SL, SV, ST)

    k_normtrip<<<NN / 4, 256, 0, stream>>>(emb, nemb, trips, tl, posR, totR, scal);
    k_contrast<<<256, 512, 0, stream>>>(nemb, labels, posR, totR);
    k_rowloss<<<NN / 4, 256, 0, stream>>>(posR, totR, labels, tl, scal);
    k_final<<<1, 64, 0, stream>>>(scal, out);
}

// Round 4
// 183.325 us; speedup vs baseline: 1.9542x; 1.9542x over previous
//
#include <hip/hip_runtime.h>

#define NN 4096
#define DD 512
#define TT 4096

typedef __bf16 bf16x8 __attribute__((ext_vector_type(8)));
typedef float f32x4 __attribute__((ext_vector_type(4)));

constexpr float INV_TEMP = 1.0f / 0.07f;

#define AS1(p) ((__attribute__((address_space(1))) const void*)(p))
#define AS3(p) ((__attribute__((address_space(3))) void*)(p))

// ---------------- normalize (fp32 -> normalized bf16) + triplet + per-row accum zero ----------------
__global__ __launch_bounds__(256) void k_normtrip(const float* __restrict__ emb,
                                                  __bf16* __restrict__ nemb,
                                                  const int* __restrict__ trip,
                                                  float* __restrict__ tl,
                                                  float* __restrict__ posR,
                                                  float* __restrict__ totR) {
    int wave = threadIdx.x >> 6, lane = threadIdx.x & 63;
    int row = blockIdx.x * 4 + wave;

    // zero this block's own rows' atomic accumulators (contrast runs after; no race)
    if (lane == 0) { posR[row] = 0.0f; totR[row] = 0.0f; }

    // ---- triplet gathers (issue early, reduce late) ----
    int ia = trip[row * 3 + 0], ip = trip[row * 3 + 1], ig = trip[row * 3 + 2];
    const float4* pa = (const float4*)(emb + (size_t)ia * DD);
    const float4* pp = (const float4*)(emb + (size_t)ip * DD);
    const float4* pn = (const float4*)(emb + (size_t)ig * DD);
    float d1 = 0.0f, d2 = 0.0f;
    #pragma unroll
    for (int j = 0; j < 2; ++j) {
        float4 a = pa[lane * 2 + j];
        float4 p = pp[lane * 2 + j];
        float4 n = pn[lane * 2 + j];
        float dx;
        dx = a.x - p.x + 1e-6f; d1 += dx * dx;
        dx = a.y - p.y + 1e-6f; d1 += dx * dx;
        dx = a.z - p.z + 1e-6f; d1 += dx * dx;
        dx = a.w - p.w + 1e-6f; d1 += dx * dx;
        dx = a.x - n.x + 1e-6f; d2 += dx * dx;
        dx = a.y - n.y + 1e-6f; d2 += dx * dx;
        dx = a.z - n.z + 1e-6f; d2 += dx * dx;
        dx = a.w - n.w + 1e-6f; d2 += dx * dx;
    }

    // ---- normalize ----
    const float4* src = (const float4*)(emb + (size_t)row * DD);
    float4 x0 = src[lane * 2 + 0];
    float4 x1 = src[lane * 2 + 1];
    float ss = x0.x * x0.x + x0.y * x0.y + x0.z * x0.z + x0.w * x0.w +
               x1.x * x1.x + x1.y * x1.y + x1.z * x1.z + x1.w * x1.w;
    #pragma unroll
    for (int m = 1; m < 64; m <<= 1) ss += __shfl_xor(ss, m, 64);
    float inv = 1.0f / fmaxf(sqrtf(ss), 1e-8f);
    bf16x8 v;
    v[0] = (__bf16)(x0.x * inv); v[1] = (__bf16)(x0.y * inv);
    v[2] = (__bf16)(x0.z * inv); v[3] = (__bf16)(x0.w * inv);
    v[4] = (__bf16)(x1.x * inv); v[5] = (__bf16)(x1.y * inv);
    v[6] = (__bf16)(x1.z * inv); v[7] = (__bf16)(x1.w * inv);
    *(bf16x8*)(nemb + (size_t)row * DD + lane * 8) = v;

    // ---- triplet reduce + store ----
    #pragma unroll
    for (int m = 1; m < 64; m <<= 1) {
        d1 += __shfl_xor(d1, m, 64);
        d2 += __shfl_xor(d2, m, 64);
    }
    if (lane == 0) tl[row] = fmaxf(sqrtf(d1) - sqrtf(d2) + 0.5f, 0.0f);
}

// ---------------- contrast: 256x256 tile, BK=64, 8-wave, 8-phase pipelined ----------------
// Main loop = round-2 proven structure (per-phase B loads, 48 frag-VGPRs; P1-end vmcnt(6),
// P4-end vmcnt(8); tail 6,4,0; end-of-phase barrier only — hazards covered by per-wave
// vmcnt -> barrier). Epilogue = 2-stage lane reduce + spread per-row atomics (no 2MB
// partial round-trip, no 4-stage shuffle tail).

#define VMW(N) asm volatile("s_waitcnt vmcnt(" #N ")" ::: "memory")
#define NOVM ((void)0)

#define STAGE_A(T, H) do { \
    __builtin_amdgcn_global_load_lds(AS1(gA0 + (size_t)((H) * 128) * DD + (T) * 64), \
                                     AS3(lA0 + (((T) & 1) * 2 + (H)) * 8192), 16, 0, 0); \
    __builtin_amdgcn_global_load_lds(AS1(gA0 + (size_t)((H) * 128 + 8) * DD + (T) * 64), \
                                     AS3(lA0 + (((T) & 1) * 2 + (H)) * 8192 + 512), 16, 0, 0); \
} while (0)

#define STAGE_B(T, H) do { \
    __builtin_amdgcn_global_load_lds(AS1(gB0 + (size_t)((H) * 128) * DD + (T) * 64), \
                                     AS3(lB0 + (((T) & 1) * 2 + (H)) * 8192), 16, 0, 0); \
    __builtin_amdgcn_global_load_lds(AS1(gB0 + (size_t)((H) * 128 + 8) * DD + (T) * 64), \
                                     AS3(lB0 + (((T) & 1) * 2 + (H)) * 8192 + 512), 16, 0, 0); \
} while (0)

#define PHASE(PAR, LOADA, QM, QN, STAGE_STMT, VM_STMT) do { \
    const __bf16* aB_ = aSm + ((PAR) * 2 + (QM)) * 8192; \
    const __bf16* bB_ = bSm + ((PAR) * 2 + (QN)) * 8192; \
    if (LOADA) { \
        _Pragma("unroll") \
        for (int fm_ = 0; fm_ < 4; ++fm_) { \
            af[fm_][0] = *(const bf16x8*)(aB_ + fm_ * 1024 + rdA0); \
            af[fm_][1] = *(const bf16x8*)(aB_ + fm_ * 1024 + rdA1); \
        } \
    } \
    _Pragma("unroll") \
    for (int fn_ = 0; fn_ < 2; ++fn_) { \
        bfr[fn_][0] = *(const bf16x8*)(bB_ + fn_ * 1024 + rdB0); \
        bfr[fn_][1] = *(const bf16x8*)(bB_ + fn_ * 1024 + rdB1); \
    } \
    STAGE_STMT; \
    asm volatile("s_waitcnt lgkmcnt(0)" ::: "memory"); \
    __builtin_amdgcn_sched_barrier(0); \
    __builtin_amdgcn_s_setprio(1); \
    _Pragma("unroll") \
    for (int kc_ = 0; kc_ < 2; ++kc_) { \
        _Pragma("unroll") \
        for (int fm_ = 0; fm_ < 4; ++fm_) { \
            _Pragma("unroll") \
            for (int fn_ = 0; fn_ < 2; ++fn_) \
                acc[QM][QN][fm_][fn_] = __builtin_amdgcn_mfma_f32_16x16x32_bf16( \
                    af[fm_][kc_], bfr[fn_][kc_], acc[QM][QN][fm_][fn_], 0, 0, 0); \
        } \
    } \
    __builtin_amdgcn_s_setprio(0); \
    __builtin_amdgcn_sched_barrier(0); \
    VM_STMT; \
    asm volatile("" ::: "memory"); \
    __builtin_amdgcn_s_barrier(); \
} while (0)

#define GROUP(G, S12, S34, VM1, VM4) do { \
    PHASE((G) & 1, 1, 0, 0, { if (S12) STAGE_A((G) + 1, 1); }, VM1); \
    PHASE((G) & 1, 0, 0, 1, { if (S12) STAGE_B((G) + 1, 1); }, NOVM); \
    PHASE((G) & 1, 1, 1, 0, { if (S34) STAGE_A((G) + 2, 0); }, NOVM); \
    PHASE((G) & 1, 0, 1, 1, { if (S34) STAGE_B((G) + 2, 0); }, VM4); \
} while (0)

__global__ __launch_bounds__(512, 2) void k_contrast(const __bf16* __restrict__ nemb,
                                                     const int* __restrict__ labels,
                                                     float* __restrict__ posR,
                                                     float* __restrict__ totR) {
    __shared__ __attribute__((aligned(16))) __bf16 aSm[4 * 8192];
    __shared__ __attribute__((aligned(16))) __bf16 bSm[4 * 8192];
    __shared__ int rlab[256];
    __shared__ int clab[256];

    int tid = threadIdx.x;
    int lane = tid & 63, wave = tid >> 6;
    int wr = wave >> 2, wc = wave & 3;
    int l15 = lane & 15, quad = lane >> 4;
    int swz = l15 & 7;

    // XCD-aware 2D swizzle: each XCD (bid&7) owns a 4x8 (rowblk x colblk) region.
    int bid = blockIdx.x;
    int xcd = bid & 7, idx = bid >> 3;
    int rowblk = (xcd >> 1) * 4 + (idx >> 3);
    int colblk = (xcd & 1) * 8 + (idx & 7);
    int row0 = rowblk * 256, col0 = colblk * 256;

    if (tid < 256) rlab[tid] = labels[row0 + tid];
    else           clab[tid - 256] = labels[col0 + tid - 256];

    // staging geometry: wave stages rows [wave*16, wave*16+16) of each 128-row half-tile.
    // LDS dest linear; SOURCE 16B-chunk pre-swizzled chunk ^= row&7 (involution w/ ds_read).
    int srow = wave * 16 + ((tid >> 3) & 7);
    int scol = ((tid & 7) ^ ((tid >> 3) & 7)) * 8;
    const __bf16* gA0 = nemb + (size_t)(row0 + srow) * DD + scol;
    const __bf16* gB0 = nemb + (size_t)(col0 + srow) * DD + scol;
    __bf16* lA0 = aSm + wave * 1024 + (tid & 63) * 8;
    __bf16* lB0 = bSm + wave * 1024 + (tid & 63) * 8;

    // ds_read offsets (elements), kc0/kc1 variants; fm/fn add compile-time +1024*k
    int rdA0 = (wr * 64 + l15) * 64 + ((quad ^ swz) * 8);
    int rdA1 = (wr * 64 + l15) * 64 + (((4 + quad) ^ swz) * 8);
    int rdB0 = (wc * 32 + l15) * 64 + ((quad ^ swz) * 8);
    int rdB1 = (wc * 32 + l15) * 64 + (((4 + quad) ^ swz) * 8);

    f32x4 acc[2][2][4][2];
    #pragma unroll
    for (int a = 0; a < 2; ++a)
        #pragma unroll
        for (int b = 0; b < 2; ++b)
            #pragma unroll
            for (int c = 0; c < 4; ++c)
                #pragma unroll
                for (int d = 0; d < 2; ++d) {
                    f32x4 z = {0.0f, 0.0f, 0.0f, 0.0f};
                    acc[a][b][c][d] = z;
                }

    bf16x8 af[4][2], bfr[2][2];

    // prologue: 6 half-tiles; vmcnt(8) -> Ah0(0), Bh0(0) resident
    STAGE_A(0, 0); STAGE_B(0, 0);
    STAGE_A(0, 1); STAGE_B(0, 1);
    STAGE_A(1, 0); STAGE_B(1, 0);
    VMW(8);
    asm volatile("" ::: "memory");
    __builtin_amdgcn_s_barrier();

    GROUP(0, 1, 1, VMW(6), VMW(8));
    GROUP(1, 1, 1, VMW(6), VMW(8));
    GROUP(2, 1, 1, VMW(6), VMW(8));
    GROUP(3, 1, 1, VMW(6), VMW(8));
    GROUP(4, 1, 1, VMW(6), VMW(8));
    GROUP(5, 1, 1, VMW(6), VMW(8));
    GROUP(6, 1, 0, VMW(6), VMW(4));
    GROUP(7, 0, 0, VMW(0), NOVM);

    // ---- epilogue: exp, mask, 2-stage lane reduce, per-row atomic accumulate ----
    #pragma unroll
    for (int qm = 0; qm < 2; ++qm)
    #pragma unroll
    for (int fm = 0; fm < 4; ++fm) {
        int rloc = qm * 128 + wr * 64 + fm * 16 + quad * 4;
        int gibase = row0 + rloc;
        int rl[4];
        #pragma unroll
        for (int v = 0; v < 4; ++v) rl[v] = rlab[rloc + v];
        float tv[4] = {0, 0, 0, 0}, pv[4] = {0, 0, 0, 0};
        #pragma unroll
        for (int qn = 0; qn < 2; ++qn)
        #pragma unroll
        for (int fn = 0; fn < 2; ++fn) {
            int cloc = qn * 128 + wc * 32 + fn * 16 + l15;
            int cl = clab[cloc];
            int gj = col0 + cloc;
            f32x4 a = acc[qm][qn][fm][fn];
            #pragma unroll
            for (int v = 0; v < 4; ++v) {
                float e = __expf(a[v] * INV_TEMP);
                tv[v] += e;
                bool match = (rl[v] == cl) && ((gibase + v) != gj);
                pv[v] += match ? e : 0.0f;
            }
        }
        #pragma unroll
        for (int m = 1; m < 4; m <<= 1) {
            #pragma unroll
            for (int v = 0; v < 4; ++v) {
                tv[v] += __shfl_xor(tv[v], m, 64);
                pv[v] += __shfl_xor(pv[v], m, 64);
            }
        }
        if ((l15 & 3) == 0) {
            #pragma unroll
            for (int v = 0; v < 4; ++v) {
                atomicAdd(&totR[gibase + v], tv[v]);
                atomicAdd(&posR[gibase + v], pv[v]);
            }
        }
    }
}

// ---------------- single-block finale: LDS label histogram -> validity, row losses, output ----
// Validity: pos_mask row-sum > 0  <=>  label multiplicity > 1 (labels in [0,256)).
// One block, 1024 threads x 4 rows; zero cross-block atomics (fixes the 159us/22ms
// same-address-atomic serialization of the previous round).
__global__ __launch_bounds__(1024) void k_rowfinal(const float* __restrict__ posR,
                                                   const float* __restrict__ totR,
                                                   const int* __restrict__ labels,
                                                   const float* __restrict__ tl,
                                                   float* __restrict__ out) {
    __shared__ int hist[256];
    __shared__ float red[3][16];
    int tid = threadIdx.x;
    if (tid < 256) hist[tid] = 0;
    __syncthreads();
    int lab[4];
    #pragma unroll
    for (int j = 0; j < 4; ++j) {
        lab[j] = labels[tid + j * 1024];
        atomicAdd(&hist[lab[j]], 1);
    }
    __syncthreads();
    float sl = 0.0f, sv = 0.0f, st = 0.0f;
    #pragma unroll
    for (int j = 0; j < 4; ++j) {
        int row = tid + j * 1024;
        bool valid = hist[lab[j]] > 1;   // counts self; >1 means a positive exists
        float p = posR[row], t = totR[row];
        float loss = valid ? -logf(p / (t + 1e-8f) + 1e-8f) : 0.0f;
        sl += loss;
        sv += valid ? 1.0f : 0.0f;
        st += tl[row];
    }
    #pragma unroll
    for (int m = 1; m < 64; m <<= 1) {
        sl += __shfl_xor(sl, m, 64);
        sv += __shfl_xor(sv, m, 64);
        st += __shfl_xor(st, m, 64);
    }
    int lane = tid & 63, wave = tid >> 6;
    if (lane == 0) { red[0][wave] = sl; red[1][wave] = sv; red[2][wave] = st; }
    __syncthreads();
    if (tid == 0) {
        float SL = 0.0f, SV = 0.0f, ST = 0.0f;
        #pragma unroll
        for (int w = 0; w < 16; ++w) { SL += red[0][w]; SV += red[1][w]; ST += red[2][w]; }
        float cont = (SV > 0.0f) ? (SL / SV) : 0.0f;
        float trip = ST * (1.0f / (float)TT);
        out[0] = cont + 0.3f * trip;
        out[1] = cont;
        out[2] = trip;
    }
}

extern "C" void kernel_launch(void* const* d_in, const int* in_sizes, int n_in,
                              void* d_out, int out_size, void* d_ws, size_t ws_size,
                              hipStream_t stream) {
    const float* emb = (const float*)d_in[0];
    const int* labels = (const int*)d_in[1];
    const int* trips = (const int*)d_in[2];
    float* out = (float*)d_out;
    char* ws = (char*)d_ws;

    __bf16* nemb = (__bf16*)(ws);                  // 4096*512*2 = 4194304 B
    float* posR  = (float*)(ws + 4194304);         // 16384 B
    float* totR  = (float*)(ws + 4210688);         // 16384 B
    float* tl    = (float*)(ws + 4227072);         // 16384 B

    k_normtrip<<<NN / 4, 256, 0, stream>>>(emb, nemb, trips, tl, posR, totR);
    k_contrast<<<256, 512, 0, stream>>>(nemb, labels, posR, totR);
    k_rowfinal<<<1, 1024, 0, stream>>>(posR, totR, labels, tl, out);
}

// Round 6
// 100.264 us; speedup vs baseline: 3.5731x; 1.8284x over previous
//
#include <hip/hip_runtime.h>

#define NN 4096
#define DD 512
#define TT 4096

typedef __bf16 bf16x8 __attribute__((ext_vector_type(8)));
typedef float f32x4 __attribute__((ext_vector_type(4)));

constexpr float INV_TEMP = 1.0f / 0.07f;

#define AS1(p) ((__attribute__((address_space(1))) const void*)(p))
#define AS3(p) ((__attribute__((address_space(3))) void*)(p))

// ---------------- normalize (fp32 -> normalized bf16) + triplet, fused ----------------
__global__ __launch_bounds__(256) void k_normtrip(const float* __restrict__ emb,
                                                  __bf16* __restrict__ nemb,
                                                  const int* __restrict__ trip,
                                                  float* __restrict__ tl) {
    int wave = threadIdx.x >> 6, lane = threadIdx.x & 63;
    int row = blockIdx.x * 4 + wave;

    // ---- triplet gathers (issue early, reduce late) ----
    int ia = trip[row * 3 + 0], ip = trip[row * 3 + 1], ig = trip[row * 3 + 2];
    const float4* pa = (const float4*)(emb + (size_t)ia * DD);
    const float4* pp = (const float4*)(emb + (size_t)ip * DD);
    const float4* pn = (const float4*)(emb + (size_t)ig * DD);
    float d1 = 0.0f, d2 = 0.0f;
    #pragma unroll
    for (int j = 0; j < 2; ++j) {
        float4 a = pa[lane * 2 + j];
        float4 p = pp[lane * 2 + j];
        float4 n = pn[lane * 2 + j];
        float dx;
        dx = a.x - p.x + 1e-6f; d1 += dx * dx;
        dx = a.y - p.y + 1e-6f; d1 += dx * dx;
        dx = a.z - p.z + 1e-6f; d1 += dx * dx;
        dx = a.w - p.w + 1e-6f; d1 += dx * dx;
        dx = a.x - n.x + 1e-6f; d2 += dx * dx;
        dx = a.y - n.y + 1e-6f; d2 += dx * dx;
        dx = a.z - n.z + 1e-6f; d2 += dx * dx;
        dx = a.w - n.w + 1e-6f; d2 += dx * dx;
    }

    // ---- normalize ----
    const float4* src = (const float4*)(emb + (size_t)row * DD);
    float4 x0 = src[lane * 2 + 0];
    float4 x1 = src[lane * 2 + 1];
    float ss = x0.x * x0.x + x0.y * x0.y + x0.z * x0.z + x0.w * x0.w +
               x1.x * x1.x + x1.y * x1.y + x1.z * x1.z + x1.w * x1.w;
    #pragma unroll
    for (int m = 1; m < 64; m <<= 1) ss += __shfl_xor(ss, m, 64);
    float inv = 1.0f / fmaxf(sqrtf(ss), 1e-8f);
    bf16x8 v;
    v[0] = (__bf16)(x0.x * inv); v[1] = (__bf16)(x0.y * inv);
    v[2] = (__bf16)(x0.z * inv); v[3] = (__bf16)(x0.w * inv);
    v[4] = (__bf16)(x1.x * inv); v[5] = (__bf16)(x1.y * inv);
    v[6] = (__bf16)(x1.z * inv); v[7] = (__bf16)(x1.w * inv);
    *(bf16x8*)(nemb + (size_t)row * DD + lane * 8) = v;

    // ---- triplet reduce + store ----
    #pragma unroll
    for (int m = 1; m < 64; m <<= 1) {
        d1 += __shfl_xor(d1, m, 64);
        d2 += __shfl_xor(d2, m, 64);
    }
    if (lane == 0) tl[row] = fmaxf(sqrtf(d1) - sqrtf(d2) + 0.5f, 0.0f);
}

// ---------------- contrast: 256x256 tile, BK=64, 8-wave, 8-phase pipelined ----------------
// Main loop = round-2 verified structure (per-phase B loads; P1-end vmcnt(6), P4-end
// vmcnt(8); tail 6,4,0; single end-of-phase barrier — hazards covered by per-wave
// vmcnt -> barrier). Epilogue = round-2 verified path: 4-stage l15 shuffle reduce +
// PLAIN stores to 64 partial slots/row (each (row,slot) written exactly once by one
// lane — zero contention; NO float atomics anywhere: float atomicAdd compiles to a
// CAS retry loop and serialized for 122-132us in round 4).

#define VMW(N) asm volatile("s_waitcnt vmcnt(" #N ")" ::: "memory")
#define NOVM ((void)0)

#define STAGE_A(T, H) do { \
    __builtin_amdgcn_global_load_lds(AS1(gA0 + (size_t)((H) * 128) * DD + (T) * 64), \
                                     AS3(lA0 + (((T) & 1) * 2 + (H)) * 8192), 16, 0, 0); \
    __builtin_amdgcn_global_load_lds(AS1(gA0 + (size_t)((H) * 128 + 8) * DD + (T) * 64), \
                                     AS3(lA0 + (((T) & 1) * 2 + (H)) * 8192 + 512), 16, 0, 0); \
} while (0)

#define STAGE_B(T, H) do { \
    __builtin_amdgcn_global_load_lds(AS1(gB0 + (size_t)((H) * 128) * DD + (T) * 64), \
                                     AS3(lB0 + (((T) & 1) * 2 + (H)) * 8192), 16, 0, 0); \
    __builtin_amdgcn_global_load_lds(AS1(gB0 + (size_t)((H) * 128 + 8) * DD + (T) * 64), \
                                     AS3(lB0 + (((T) & 1) * 2 + (H)) * 8192 + 512), 16, 0, 0); \
} while (0)

#define PHASE(PAR, LOADA, QM, QN, STAGE_STMT, VM_STMT) do { \
    const __bf16* aB_ = aSm + ((PAR) * 2 + (QM)) * 8192; \
    const __bf16* bB_ = bSm + ((PAR) * 2 + (QN)) * 8192; \
    if (LOADA) { \
        _Pragma("unroll") \
        for (int fm_ = 0; fm_ < 4; ++fm_) { \
            af[fm_][0] = *(const bf16x8*)(aB_ + fm_ * 1024 + rdA0); \
            af[fm_][1] = *(const bf16x8*)(aB_ + fm_ * 1024 + rdA1); \
        } \
    } \
    _Pragma("unroll") \
    for (int fn_ = 0; fn_ < 2; ++fn_) { \
        bfr[fn_][0] = *(const bf16x8*)(bB_ + fn_ * 1024 + rdB0); \
        bfr[fn_][1] = *(const bf16x8*)(bB_ + fn_ * 1024 + rdB1); \
    } \
    STAGE_STMT; \
    asm volatile("s_waitcnt lgkmcnt(0)" ::: "memory"); \
    __builtin_amdgcn_sched_barrier(0); \
    __builtin_amdgcn_s_setprio(1); \
    _Pragma("unroll") \
    for (int kc_ = 0; kc_ < 2; ++kc_) { \
        _Pragma("unroll") \
        for (int fm_ = 0; fm_ < 4; ++fm_) { \
            _Pragma("unroll") \
            for (int fn_ = 0; fn_ < 2; ++fn_) \
                acc[QM][QN][fm_][fn_] = __builtin_amdgcn_mfma_f32_16x16x32_bf16( \
                    af[fm_][kc_], bfr[fn_][kc_], acc[QM][QN][fm_][fn_], 0, 0, 0); \
        } \
    } \
    __builtin_amdgcn_s_setprio(0); \
    __builtin_amdgcn_sched_barrier(0); \
    VM_STMT; \
    asm volatile("" ::: "memory"); \
    __builtin_amdgcn_s_barrier(); \
} while (0)

#define GROUP(G, S12, S34, VM1, VM4) do { \
    PHASE((G) & 1, 1, 0, 0, { if (S12) STAGE_A((G) + 1, 1); }, VM1); \
    PHASE((G) & 1, 0, 0, 1, { if (S12) STAGE_B((G) + 1, 1); }, NOVM); \
    PHASE((G) & 1, 1, 1, 0, { if (S34) STAGE_A((G) + 2, 0); }, NOVM); \
    PHASE((G) & 1, 0, 1, 1, { if (S34) STAGE_B((G) + 2, 0); }, VM4); \
} while (0)

__global__ __launch_bounds__(512, 2) void k_contrast(const __bf16* __restrict__ nemb,
                                                     const int* __restrict__ labels,
                                                     float* __restrict__ posP,
                                                     float* __restrict__ totP) {
    __shared__ __attribute__((aligned(16))) __bf16 aSm[4 * 8192];
    __shared__ __attribute__((aligned(16))) __bf16 bSm[4 * 8192];
    __shared__ int rlab[256];
    __shared__ int clab[256];

    int tid = threadIdx.x;
    int lane = tid & 63, wave = tid >> 6;
    int wr = wave >> 2, wc = wave & 3;
    int l15 = lane & 15, quad = lane >> 4;
    int swz = l15 & 7;

    // XCD-aware 2D swizzle: each XCD (bid&7) owns a 4x8 (rowblk x colblk) region.
    int bid = blockIdx.x;
    int xcd = bid & 7, idx = bid >> 3;
    int rowblk = (xcd >> 1) * 4 + (idx >> 3);
    int colblk = (xcd & 1) * 8 + (idx & 7);
    int row0 = rowblk * 256, col0 = colblk * 256;

    if (tid < 256) rlab[tid] = labels[row0 + tid];
    else           clab[tid - 256] = labels[col0 + tid - 256];

    // staging geometry: wave stages rows [wave*16, wave*16+16) of each 128-row half-tile.
    // LDS dest linear; SOURCE 16B-chunk pre-swizzled chunk ^= row&7 (involution w/ ds_read).
    int srow = wave * 16 + ((tid >> 3) & 7);
    int scol = ((tid & 7) ^ ((tid >> 3) & 7)) * 8;
    const __bf16* gA0 = nemb + (size_t)(row0 + srow) * DD + scol;
    const __bf16* gB0 = nemb + (size_t)(col0 + srow) * DD + scol;
    __bf16* lA0 = aSm + wave * 1024 + (tid & 63) * 8;
    __bf16* lB0 = bSm + wave * 1024 + (tid & 63) * 8;

    // ds_read offsets (elements), kc0/kc1 variants; fm/fn add compile-time +1024*k
    int rdA0 = (wr * 64 + l15) * 64 + ((quad ^ swz) * 8);
    int rdA1 = (wr * 64 + l15) * 64 + (((4 + quad) ^ swz) * 8);
    int rdB0 = (wc * 32 + l15) * 64 + ((quad ^ swz) * 8);
    int rdB1 = (wc * 32 + l15) * 64 + (((4 + quad) ^ swz) * 8);

    f32x4 acc[2][2][4][2];
    #pragma unroll
    for (int a = 0; a < 2; ++a)
        #pragma unroll
        for (int b = 0; b < 2; ++b)
            #pragma unroll
            for (int c = 0; c < 4; ++c)
                #pragma unroll
                for (int d = 0; d < 2; ++d) {
                    f32x4 z = {0.0f, 0.0f, 0.0f, 0.0f};
                    acc[a][b][c][d] = z;
                }

    bf16x8 af[4][2], bfr[2][2];

    // prologue: 6 half-tiles; vmcnt(8) -> Ah0(0), Bh0(0) resident
    STAGE_A(0, 0); STAGE_B(0, 0);
    STAGE_A(0, 1); STAGE_B(0, 1);
    STAGE_A(1, 0); STAGE_B(1, 0);
    VMW(8);
    asm volatile("" ::: "memory");
    __builtin_amdgcn_s_barrier();

    GROUP(0, 1, 1, VMW(6), VMW(8));
    GROUP(1, 1, 1, VMW(6), VMW(8));
    GROUP(2, 1, 1, VMW(6), VMW(8));
    GROUP(3, 1, 1, VMW(6), VMW(8));
    GROUP(4, 1, 1, VMW(6), VMW(8));
    GROUP(5, 1, 1, VMW(6), VMW(8));
    GROUP(6, 1, 0, VMW(6), VMW(4));
    GROUP(7, 0, 0, VMW(0), NOVM);

    // ---- epilogue: exp, mask, 4-stage l15 shuffle reduce, plain stores (64 slots/row) ----
    #pragma unroll
    for (int qm = 0; qm < 2; ++qm)
    #pragma unroll
    for (int fm = 0; fm < 4; ++fm) {
        int rloc = qm * 128 + wr * 64 + fm * 16 + quad * 4;
        int gibase = row0 + rloc;
        int rl[4];
        #pragma unroll
        for (int v = 0; v < 4; ++v) rl[v] = rlab[rloc + v];
        float tv[4] = {0, 0, 0, 0}, pv[4] = {0, 0, 0, 0};
        #pragma unroll
        for (int qn = 0; qn < 2; ++qn)
        #pragma unroll
        for (int fn = 0; fn < 2; ++fn) {
            int cloc = qn * 128 + wc * 32 + fn * 16 + l15;
            int cl = clab[cloc];
            int gj = col0 + cloc;
            f32x4 a = acc[qm][qn][fm][fn];
            #pragma unroll
            for (int v = 0; v < 4; ++v) {
                float e = __expf(a[v] * INV_TEMP);
                tv[v] += e;
                bool match = (rl[v] == cl) && ((gibase + v) != gj);
                pv[v] += match ? e : 0.0f;
            }
        }
        #pragma unroll
        for (int m = 1; m < 16; m <<= 1) {
            #pragma unroll
            for (int v = 0; v < 4; ++v) {
                tv[v] += __shfl_xor(tv[v], m, 64);
                pv[v] += __shfl_xor(pv[v], m, 64);
            }
        }
        if (l15 == 0) {
            #pragma unroll
            for (int v = 0; v < 4; ++v) {
                int o = (gibase + v) * 64 + colblk * 4 + wc;
                posP[o] = pv[v];
                totP[o] = tv[v];
            }
        }
    }
}

// ---------------- per-row loss: LDS label histogram for validity + 64-slot reduce ----------
// Validity: pos_mask row-sum > 0  <=>  label multiplicity > 1 (labels in [0,256)).
// Histogram built per-block from all 4096 labels (LDS int atomics, ~16/bin — cheap).
// No global atomics anywhere.
__global__ __launch_bounds__(256) void k_rowloss(const float* __restrict__ posP,
                                                 const float* __restrict__ totP,
                                                 const int* __restrict__ labels,
                                                 float* __restrict__ rloss,
                                                 float* __restrict__ rvalid) {
    __shared__ int hist[256];
    int tid = threadIdx.x;
    hist[tid] = 0;
    __syncthreads();
    #pragma unroll
    for (int j = 0; j < 16; ++j)
        atomicAdd(&hist[labels[tid + j * 256]], 1);
    __syncthreads();

    int wave = tid >> 6, lane = tid & 63;
    int row = blockIdx.x * 4 + wave;
    float p = posP[row * 64 + lane];
    float t = totP[row * 64 + lane];
    #pragma unroll
    for (int m = 1; m < 64; m <<= 1) {
        p += __shfl_xor(p, m, 64);
        t += __shfl_xor(t, m, 64);
    }
    if (lane == 0) {
        bool valid = hist[labels[row]] > 1;   // counts self; >1 => a positive exists
        float loss = valid ? -logf(p / (t + 1e-8f) + 1e-8f) : 0.0f;
        rloss[row] = loss;
        rvalid[row] = valid ? 1.0f : 0.0f;
    }
}

// ---------------- final reduction ----------------
__global__ __launch_bounds__(256) void k_final(const float* __restrict__ rloss,
                                               const float* __restrict__ rvalid,
                                               const float* __restrict__ tl,
                                               float* __restrict__ out) {
    int tid = threadIdx.x;
    float sl = 0.0f, sv = 0.0f, st = 0.0f;
    for (int i = tid; i < NN; i += 256) {
        sl += rloss[i];
        sv += rvalid[i];
        st += tl[i];
    }
    #pragma unroll
    for (int m = 1; m < 64; m <<= 1) {
        sl += __shfl_xor(sl, m, 64);
        sv += __shfl_xor(sv, m, 64);
        st += __shfl_xor(st, m, 64);
    }
    __shared__ float red[3][4];
    int lane = tid & 63, wave = tid >> 6;
    if (lane == 0) { red[0][wave] = sl; red[1][wave] = sv; red[2][wave] = st; }
    __syncthreads();
    if (tid == 0) {
        float SL = red[0][0] + red[0][1] + red[0][2] + red[0][3];
        float SV = red[1][0] + red[1][1] + red[1][2] + red[1][3];
        float ST = red[2][0] + red[2][1] + red[2][2] + red[2][3];
        float cont = (SV > 0.0f) ? (SL / SV) : 0.0f;
        float trip = ST * (1.0f / (float)TT);
        out[0] = cont + 0.3f * trip;
        out[1] = cont;
        out[2] = trip;
    }
}

extern "C" void kernel_launch(void* const* d_in, const int* in_sizes, int n_in,
                              void* d_out, int out_size, void* d_ws, size_t ws_size,
                              hipStream_t stream) {
    const float* emb = (const float*)d_in[0];
    const int* labels = (const int*)d_in[1];
    const int* trips = (const int*)d_in[2];
    float* out = (float*)d_out;
    char* ws = (char*)d_ws;

    __bf16* nemb  = (__bf16*)(ws);                 // 4096*512*2 = 4194304 B
    float* posP   = (float*)(ws + 4194304);        // 4096*64*4  = 1048576 B
    float* totP   = (float*)(ws + 5242880);        // 1048576 B
    float* rloss  = (float*)(ws + 6291456);        // 16384 B
    float* rvalid = (float*)(ws + 6307840);        // 16384 B
    float* tl     = (float*)(ws + 6324224);        // 16384 B

    k_normtrip<<<NN / 4, 256, 0, stream>>>(emb, nemb, trips, tl);
    k_contrast<<<256, 512, 0, stream>>>(nemb, labels, posP, totP);
    k_rowloss<<<NN / 4, 256, 0, stream>>>(posP, totP, labels, rloss, rvalid);
    k_final<<<1, 256, 0, stream>>>(rloss, rvalid, tl, out);
}